// Round 1
// baseline (6243.970 us; speedup 1.0000x reference)
//
#include <hip/hip_runtime.h>

// ---------------------------------------------------------------------------
// Tube_fps forward. All GEMM-shaped compute on split-bf16 3-pass MFMA
// (x = hi + lo bf16; acc += Ah*Bh + Ah*Bl + Al*Bh; dropped term ~2^-16 rel).
// Attention: MFMA flash, P stored hi-only (err ~0.2% on attn out, diluted).
// fp32 state: seq (8,1034,768), z (8,834,768). Everything else bf16 planes.
// FFN restructured for occupancy: all 8 samples per dispatch; conv1 split in
// J-halves, conv2 split in K-halves accumulating into z (grid 336->1344 blks).
// ---------------------------------------------------------------------------

typedef short bf16x8 __attribute__((ext_vector_type(8)));
typedef float f32x4 __attribute__((ext_vector_type(4)));

__device__ __forceinline__ void split_bf16(float f, ushort& h, ushort& l) {
  uint u = __float_as_uint(f);
  uint rh = (u + 0x7FFFu + ((u >> 16) & 1u)) & 0xFFFF0000u;
  h = (ushort)(rh >> 16);
  float fl = f - __uint_as_float(rh);
  uint ul = __float_as_uint(fl);
  l = (ushort)((ul + 0x7FFFu + ((ul >> 16) & 1u)) >> 16);
}

__device__ __forceinline__ ushort bf16_rnd(float f) {
  uint u = __float_as_uint(f);
  return (ushort)((u + 0x7FFFu + ((u >> 16) & 1u)) >> 16);
}

__device__ __forceinline__ float gelu_exact(float v) {
  return 0.5f * v * (1.f + erff(v * 0.70710678118654752f));
}

// ---------------- generic fp32 -> bf16 hi/lo split -------------------------
__global__ void wsplit_kernel(const float* __restrict__ src, ushort* __restrict__ h,
                              ushort* __restrict__ l, int n4) {
  int i = blockIdx.x * 256 + threadIdx.x;
  if (i >= n4) return;
  float4 v = *(const float4*)(src + (size_t)i * 4);
  ushort hh[4], ll[4];
  split_bf16(v.x, hh[0], ll[0]);
  split_bf16(v.y, hh[1], ll[1]);
  split_bf16(v.z, hh[2], ll[2]);
  split_bf16(v.w, hh[3], ll[3]);
  *(ushort4*)(h + (size_t)i * 4) = make_ushort4(hh[0], hh[1], hh[2], hh[3]);
  *(ushort4*)(l + (size_t)i * 4) = make_ushort4(ll[0], ll[1], ll[2], ll[3]);
}

// ---------------- weight trilinear resize (jax.image.resize, antialias) ----
__device__ __forceinline__ void dim_weights(int j, int O, float* w) {
  float inv = 8.0f / (float)O;
  float ks  = inv > 1.0f ? inv : 1.0f;
  float sf  = ((float)j + 0.5f) * inv - 0.5f;
  float tot = 0.f;
#pragma unroll
  for (int i = 0; i < 8; i++) {
    float xx = fabsf(sf - (float)i) / ks;
    float t  = fmaxf(0.f, 1.f - xx);
    w[i] = t; tot += t;
  }
  float r = 1.f / tot;
#pragma unroll
  for (int i = 0; i < 8; i++) w[i] *= r;
}

__global__ void resize_w_split(const float* __restrict__ src, ushort* __restrict__ dh,
                               ushort* __restrict__ dl, int OD, int OH, int OW) {
  int idx = blockIdx.x * 256 + threadIdx.x;
  int tot = 2304 * OD * OH * OW;
  if (idx >= tot) return;
  int ow = idx % OW; int t = idx / OW;
  int oh = t % OH;   t /= OH;
  int od = t % OD;   int oc = t / OD;
  float wd[8], wh[8], ww[8];
  dim_weights(od, OD, wd);
  dim_weights(oh, OH, wh);
  dim_weights(ow, OW, ww);
  const float* s = src + (size_t)oc * 512;
  float acc = 0.f;
  for (int d = 0; d < 8; d++) {
    if (wd[d] == 0.f) continue;
    for (int h = 0; h < 8; h++) {
      if (wh[h] == 0.f) continue;
      float w2 = wd[d] * wh[h];
      for (int w = 0; w < 8; w++) {
        float w3 = w2 * ww[w];
        if (w3 != 0.f) acc += w3 * s[d * 64 + h * 8 + w];
      }
    }
  }
  ushort h2, l2;
  split_bf16(acc, h2, l2);
  dh[idx] = h2; dl[idx] = l2;
}

// ---------------- im2col (split output) ------------------------------------
__global__ void im2col_split(const float* __restrict__ x, ushort* __restrict__ colh,
                             ushort* __restrict__ coll, int P, int K, int L,
                             int KD, int KH, int KW, int SD, int SH, int SW) {
  int idx = blockIdx.x * 256 + threadIdx.x;
  if (idx >= P * K) return;
  int p = idx / K;  int k = idx - p * K;
  int n = p / L;    int lp = p - n * L;
  int ld = lp / 49; int r = lp - ld * 49;
  int lh = r / 7;   int lw = r - lh * 7;
  int kvol = KD * KH * KW;
  int c = k / kvol; int r2 = k - c * kvol;
  int khw = KH * KW;
  int kd = r2 / khw; int r3 = r2 - kd * khw;
  int kh = r3 / KW;  int kw = r3 - kh * KW;
  int zd = ld * SD + kd, zh = lh * SH + kh, zw = lw * SW + kw;
  float v = x[((((size_t)n * 3 + c) * 64 + zd) * 224 + zh) * 224 + zw];
  ushort h, l;
  split_bf16(v, h, l);
  colh[(size_t)p * K + k] = h;
  coll[(size_t)p * K + k] = l;
}

// ---------------- split-bf16 3-pass MFMA GEMM ------------------------------
// C[i][j] = sum_k A[i][k]*B[j][k].  A: M x K planes, B: N x K planes.
// MODE 0: of[i*ldo+j] = acc (+bias)
// MODE 1: of[i*768+j] = acc + bias + res[i*768+j]
// MODE 2: split(acc*scale) -> oh/ol[i*768+j]
// MODE 3: row = (i/mapL)*1034 + mapOff + i%mapL; v = acc + bias (+res[row*768+j]);
//         of[row*768+j] = v; if oh: split v -> oh/ol[row*768+j]
template <int MODE>
__global__ __launch_bounds__(256) void gemm_bf3(
    const ushort* __restrict__ Ah, const ushort* __restrict__ Al,
    const ushort* __restrict__ Bh, const ushort* __restrict__ Bl,
    int M, int N, int K,
    const float* __restrict__ bias, const float* __restrict__ res, float scale,
    float* __restrict__ of, ushort* __restrict__ oh, ushort* __restrict__ ol,
    int mapL, int mapOff, int ldo) {
  __shared__ ushort ldsA[2 * 128 * 40];
  __shared__ ushort ldsB[2 * 128 * 40];
  const int tid = threadIdx.x;
  const int wave = tid >> 6, lane = tid & 63;
  const int lrow = lane & 15, kq = lane >> 4;
  const int i0 = blockIdx.y * 128;
  const int j0 = blockIdx.x * 128;
  const int wm = (wave & 1) * 64, wn = (wave >> 1) * 64;
  const int sr = tid >> 1, sp = tid & 1;

  f32x4 acc[4][4];
#pragma unroll
  for (int mi = 0; mi < 4; mi++)
#pragma unroll
    for (int ni = 0; ni < 4; ni++) acc[mi][ni] = (f32x4)0.f;

  for (int k0 = 0; k0 < K; k0 += 32) {
    __syncthreads();
    {
      uint4 d0 = make_uint4(0, 0, 0, 0), d1 = d0, d2 = d0, d3 = d0;
      if (i0 + sr < M) {
        const ushort* s = (sp ? Al : Ah) + (size_t)(i0 + sr) * K + k0;
        d0 = *(const uint4*)(const void*)s;
        d1 = *(const uint4*)(const void*)(s + 8);
        d2 = *(const uint4*)(const void*)(s + 16);
        d3 = *(const uint4*)(const void*)(s + 24);
      }
      ushort* dst = &ldsA[sp * 5120 + sr * 40];
      *(uint4*)(void*)dst = d0; *(uint4*)(void*)(dst + 8) = d1;
      *(uint4*)(void*)(dst + 16) = d2; *(uint4*)(void*)(dst + 24) = d3;
    }
    {
      uint4 d0 = make_uint4(0, 0, 0, 0), d1 = d0, d2 = d0, d3 = d0;
      if (j0 + sr < N) {
        const ushort* s = (sp ? Bl : Bh) + (size_t)(j0 + sr) * K + k0;
        d0 = *(const uint4*)(const void*)s;
        d1 = *(const uint4*)(const void*)(s + 8);
        d2 = *(const uint4*)(const void*)(s + 16);
        d3 = *(const uint4*)(const void*)(s + 24);
      }
      ushort* dst = &ldsB[sp * 5120 + sr * 40];
      *(uint4*)(void*)dst = d0; *(uint4*)(void*)(dst + 8) = d1;
      *(uint4*)(void*)(dst + 16) = d2; *(uint4*)(void*)(dst + 24) = d3;
    }
    __syncthreads();
    bf16x8 af[2][4], bf[2][4];
#pragma unroll
    for (int p = 0; p < 2; p++)
#pragma unroll
      for (int mi = 0; mi < 4; mi++)
        af[p][mi] = *(const bf16x8*)&ldsA[p * 5120 + (wm + mi * 16 + lrow) * 40 + kq * 8];
#pragma unroll
    for (int p = 0; p < 2; p++)
#pragma unroll
      for (int ni = 0; ni < 4; ni++)
        bf[p][ni] = *(const bf16x8*)&ldsB[p * 5120 + (wn + ni * 16 + lrow) * 40 + kq * 8];
#pragma unroll
    for (int mi = 0; mi < 4; mi++)
#pragma unroll
      for (int ni = 0; ni < 4; ni++)
        acc[mi][ni] = __builtin_amdgcn_mfma_f32_16x16x32_bf16(
            af[0][mi], bf[0][ni], acc[mi][ni], 0, 0, 0);
#pragma unroll
    for (int mi = 0; mi < 4; mi++)
#pragma unroll
      for (int ni = 0; ni < 4; ni++)
        acc[mi][ni] = __builtin_amdgcn_mfma_f32_16x16x32_bf16(
            af[0][mi], bf[1][ni], acc[mi][ni], 0, 0, 0);
#pragma unroll
    for (int mi = 0; mi < 4; mi++)
#pragma unroll
      for (int ni = 0; ni < 4; ni++)
        acc[mi][ni] = __builtin_amdgcn_mfma_f32_16x16x32_bf16(
            af[1][mi], bf[0][ni], acc[mi][ni], 0, 0, 0);
  }

#pragma unroll
  for (int mi = 0; mi < 4; mi++) {
#pragma unroll
    for (int r = 0; r < 4; r++) {
      int i = i0 + wm + mi * 16 + kq * 4 + r;
      if (i >= M) continue;
#pragma unroll
      for (int ni = 0; ni < 4; ni++) {
        int j = j0 + wn + ni * 16 + lrow;
        if (j >= N) continue;
        float v = acc[mi][ni][r];
        if (MODE == 0) {
          if (bias) v += bias[j];
          of[(size_t)i * ldo + j] = v;
        } else if (MODE == 1) {
          size_t oi = (size_t)i * 768 + j;
          of[oi] = v + bias[j] + res[oi];
        } else if (MODE == 2) {
          v *= scale;
          ushort h, l;
          split_bf16(v, h, l);
          size_t oi = (size_t)i * 768 + j;
          oh[oi] = h; ol[oi] = l;
        } else {
          int nn = i / mapL; int ll = i - nn * mapL;
          size_t oi = ((size_t)(nn * 1034 + mapOff + ll)) * 768 + j;
          v += bias[j];
          if (res) v += res[oi];
          of[oi] = v;
          if (oh) {
            ushort h, l;
            split_bf16(v, h, l);
            oh[oi] = h; ol[oi] = l;
          }
        }
      }
    }
  }
}

// ---------------- weight prep: W[oOff+o][cOff+c][dt] fp32 ------------------
// -> wh/wl[(dt*Jloc + o)*Cloc + c] bf16 hi/lo (a J/C sub-slab, transposed)
__global__ void wprep_kernel(const float* __restrict__ W, ushort* __restrict__ wh,
                             ushort* __restrict__ wl, int Jloc, int oOff,
                             int Cloc, int cOff, int Cfull) {
  size_t idx = (size_t)blockIdx.x * 256 + threadIdx.x;
  size_t tot = (size_t)9 * Jloc * Cloc;
  if (idx >= tot) return;
  int c = (int)(idx % Cloc);
  size_t t2 = idx / Cloc;
  int o = (int)(t2 % Jloc);
  int dt = (int)(t2 / Jloc);
  float f = W[((size_t)(oOff + o) * Cfull + (cOff + c)) * 9 + dt];
  ushort h, l;
  split_bf16(f, h, l);
  wh[idx] = h; wl[idx] = l;
}

// ---------------- ln3 + split into padded bf16 planes ----------------------
__global__ __launch_bounds__(256) void ln_split_kernel(
    const float* __restrict__ in, const float* __restrict__ g,
    const float* __restrict__ b, ushort* __restrict__ oh, ushort* __restrict__ ol) {
  int row = blockIdx.x, tid = threadIdx.x;
  int n = row / 834, t = row - n * 834;
  const float* xp = in + (size_t)row * 768;
  float v0 = xp[tid], v1 = xp[tid + 256], v2 = xp[tid + 512];
  float s = v0 + v1 + v2;
  float sq = v0 * v0 + v1 * v1 + v2 * v2;
  __shared__ float red[8];
#pragma unroll
  for (int off = 32; off >= 1; off >>= 1) {
    s += __shfl_down(s, off, 64); sq += __shfl_down(sq, off, 64);
  }
  if ((tid & 63) == 0) { red[tid >> 6] = s; red[4 + (tid >> 6)] = sq; }
  __syncthreads();
  s = red[0] + red[1] + red[2] + red[3];
  sq = red[4] + red[5] + red[6] + red[7];
  float m = s * (1.f / 768.f);
  float var = sq * (1.f / 768.f) - m * m;
  float rs = rsqrtf(var + 1e-5f);
  size_t dbase = ((size_t)(n * 842 + 4 + t)) * 768;
  ushort h, l;
  float y0 = (v0 - m) * rs * g[tid] + b[tid];
  split_bf16(y0, h, l); oh[dbase + tid] = h; ol[dbase + tid] = l;
  float y1 = (v1 - m) * rs * g[tid + 256] + b[tid + 256];
  split_bf16(y1, h, l); oh[dbase + tid + 256] = h; ol[dbase + tid + 256] = l;
  float y2 = (v2 - m) * rs * g[tid + 512] + b[tid + 512];
  split_bf16(y2, h, l); oh[dbase + tid + 512] = h; ol[dbase + tid + 512] = l;
}

// ---------------- zero pad rows of zs (8 samples) and fmid (8 slots) -------
__global__ void pad_zero8(ushort* __restrict__ zh, ushort* __restrict__ zl,
                          ushort* __restrict__ fh, ushort* __restrict__ fl) {
  int idx = blockIdx.x * 256 + threadIdx.x;
  if (idx < 49152) {
    int c = idx % 768; int t2 = idx / 768;
    int rr = t2 & 7; int n = t2 >> 3;
    int row = (rr < 4) ? rr : (834 + rr);
    size_t d = ((size_t)(n * 842 + row)) * 768 + c;
    zh[d] = 0; zl[d] = 0;
  } else {
    int k = idx - 49152;
    if (k >= 196608) return;
    int c = k % 3072; int t2 = k / 3072;
    int rr = t2 & 7; int n = t2 >> 3;
    int row = (rr < 4) ? rr : (834 + rr);
    size_t d = ((size_t)(n * 842 + row)) * 3072 + c;
    fh[d] = 0; fl[d] = 0;
  }
}

// ---------------- conv1d-as-9-shifted-GEMMs, split-bf16 MFMA ---------------
// A: padded planes, slot stride 842 rows, row stride CinA, K cols at cOff.
// W: [dt][J][K] planes. Block tile: (2*WM) t-rows x BN channels, 4 waves 2x2.
// MODE 1: v = gelu(acc+bias) -> split into fm planes (stride 3072, col jOff+o)
// MODE 2: of[(bz*834+t)*768+o] += acc (+bias if given)   [K-split accumulate]
template <int BN, int WM, int WN, int MODE>
__global__ __launch_bounds__(256) void conv_mfma(
    const ushort* __restrict__ Ah, const ushort* __restrict__ Al,
    const ushort* __restrict__ Wh, const ushort* __restrict__ Wl,
    int CinA, int cOff, int K, int J,
    const float* __restrict__ bias, int jOff,
    ushort* __restrict__ oh, ushort* __restrict__ ol,
    float* __restrict__ of) {
  constexpr int MI = WM / 16, NI = WN / 16;
  constexpr int BM = 2 * WM;
  constexpr int AR = BM + 8;
  __shared__ ushort ldsA[2 * AR * 40];
  __shared__ ushort ldsB[2 * BN * 40];
  const int tid = threadIdx.x;
  const int wave = tid >> 6, lane = tid & 63;
  const int lrow = lane & 15, kq = lane >> 4;
  const int t0 = blockIdx.x * BM;
  const int j0 = blockIdx.y * BN;
  const int bz = blockIdx.z;
  const int wm = (wave & 1) * WM;
  const int wn = (wave >> 1) * WN;

  f32x4 acc[MI][NI];
#pragma unroll
  for (int mi = 0; mi < MI; mi++)
#pragma unroll
    for (int ni = 0; ni < NI; ni++) acc[mi][ni] = (f32x4)0.f;

  for (int c0 = 0; c0 < K; c0 += 32) {
    __syncthreads();
    for (int task = tid; task < 4 * AR; task += 256) {
      int plane = task >= 2 * AR;
      int rem = task - plane * 2 * AR;
      int r = rem >> 1, h = rem & 1;
      const ushort* src = (plane ? Al : Ah) +
          ((size_t)(bz * 842 + t0 + r)) * CinA + cOff + c0 + h * 16;
      uint4 d0 = *(const uint4*)(const void*)src;
      uint4 d1 = *(const uint4*)(const void*)(src + 8);
      ushort* dst = &ldsA[plane * (AR * 40) + r * 40 + h * 16];
      *(uint4*)(void*)dst = d0;
      *(uint4*)(void*)(dst + 8) = d1;
    }
    for (int dt = 0; dt < 9; dt++) {
      if (dt > 0) __syncthreads();
      for (int task = tid; task < 4 * BN; task += 256) {
        int plane = task >= 2 * BN;
        int rem = task - plane * 2 * BN;
        int o = rem >> 1, h = rem & 1;
        const ushort* src = (plane ? Wl : Wh) +
            ((size_t)(dt * J + j0 + o)) * K + c0 + h * 16;
        uint4 d0 = *(const uint4*)(const void*)src;
        uint4 d1 = *(const uint4*)(const void*)(src + 8);
        ushort* dst = &ldsB[plane * (BN * 40) + o * 40 + h * 16];
        *(uint4*)(void*)dst = d0;
        *(uint4*)(void*)(dst + 8) = d1;
      }
      __syncthreads();
      bf16x8 af[2][MI], bf[2][NI];
#pragma unroll
      for (int p = 0; p < 2; p++)
#pragma unroll
        for (int mi = 0; mi < MI; mi++)
          af[p][mi] = *(const bf16x8*)&ldsA[p * (AR * 40) +
              (dt + wm + mi * 16 + lrow) * 40 + kq * 8];
#pragma unroll
      for (int p = 0; p < 2; p++)
#pragma unroll
        for (int ni = 0; ni < NI; ni++)
          bf[p][ni] = *(const bf16x8*)&ldsB[p * (BN * 40) +
              (wn + ni * 16 + lrow) * 40 + kq * 8];
#pragma unroll
      for (int mi = 0; mi < MI; mi++)
#pragma unroll
        for (int ni = 0; ni < NI; ni++)
          acc[mi][ni] = __builtin_amdgcn_mfma_f32_16x16x32_bf16(
              af[0][mi], bf[0][ni], acc[mi][ni], 0, 0, 0);
#pragma unroll
      for (int mi = 0; mi < MI; mi++)
#pragma unroll
        for (int ni = 0; ni < NI; ni++)
          acc[mi][ni] = __builtin_amdgcn_mfma_f32_16x16x32_bf16(
              af[0][mi], bf[1][ni], acc[mi][ni], 0, 0, 0);
#pragma unroll
      for (int mi = 0; mi < MI; mi++)
#pragma unroll
        for (int ni = 0; ni < NI; ni++)
          acc[mi][ni] = __builtin_amdgcn_mfma_f32_16x16x32_bf16(
              af[1][mi], bf[0][ni], acc[mi][ni], 0, 0, 0);
    }
  }

#pragma unroll
  for (int ni = 0; ni < NI; ni++) {
    int o = jOff + j0 + wn + ni * 16 + lrow;
    float bo = bias ? bias[o] : 0.f;
#pragma unroll
    for (int mi = 0; mi < MI; mi++) {
#pragma unroll
      for (int r = 0; r < 4; r++) {
        int t = t0 + wm + mi * 16 + kq * 4 + r;
        if (t < 834) {
          float v = acc[mi][ni][r] + bo;
          if (MODE == 1) {
            v = gelu_exact(v);
            ushort h, l;
            split_bf16(v, h, l);
            size_t d = ((size_t)(bz * 842 + 4 + t)) * 3072 + o;
            oh[d] = h; ol[d] = l;
          } else {
            size_t d = ((size_t)(bz * 834 + t)) * 768 + o;
            of[d] += v;
          }
        }
      }
    }
  }
}

// ---------------- cls/pos add ----------------------------------------------
__global__ void addpos_kernel(float* __restrict__ seq, const float* __restrict__ pos,
                              const float* __restrict__ cls) {
  int idx = blockIdx.x * 256 + threadIdx.x;
  if (idx >= 8 * 834 * 768) return;
  int c = idx % 768;
  int t = (idx / 768) % 834;
  int n = idx / (768 * 834);
  size_t off = ((size_t)(n * 1034 + t)) * 768 + c;
  float v = (t == 0) ? cls[c] : seq[off];
  seq[off] = v + pos[(size_t)t * 768 + c];
}

// ---------------- GroupNorm -> split planes --------------------------------
__global__ __launch_bounds__(256) void groupnorm_split(
    const float* __restrict__ seq, const float* __restrict__ g,
    const float* __restrict__ b, ushort* __restrict__ oh, ushort* __restrict__ ol) {
  int blk = blockIdx.x;
  int n = blk >> 5, grp = blk & 31;
  int tid = threadIdx.x;
  float s = 0.f, sq = 0.f;
  for (int e = tid; e < 20016; e += 256) {
    int t = e / 24; int cc = e - t * 24;
    float v = seq[((size_t)(n * 1034 + t)) * 768 + grp * 24 + cc];
    s += v; sq += v * v;
  }
  __shared__ float red[8];
#pragma unroll
  for (int off = 32; off >= 1; off >>= 1) {
    s += __shfl_down(s, off, 64); sq += __shfl_down(sq, off, 64);
  }
  if ((tid & 63) == 0) { red[tid >> 6] = s; red[4 + (tid >> 6)] = sq; }
  __syncthreads();
  s = red[0] + red[1] + red[2] + red[3];
  sq = red[4] + red[5] + red[6] + red[7];
  float m = s * (1.f / 20016.f);
  float var = sq * (1.f / 20016.f) - m * m;
  float rs = rsqrtf(var + 1e-6f);
  for (int e = tid; e < 20016; e += 256) {
    int t = e / 24; int cc = e - t * 24;
    int c = grp * 24 + cc;
    float v = seq[((size_t)(n * 1034 + t)) * 768 + c];
    float y = (v - m) * rs * g[c] + b[c];
    ushort h, l;
    split_bf16(y, h, l);
    size_t d = ((size_t)(n * 834 + t)) * 768 + c;
    oh[d] = h; ol[d] = l;
  }
}

// ---------------- LayerNorm per row -> split planes ------------------------
__global__ __launch_bounds__(256) void ln_rows_split(
    const float* __restrict__ in, const float* __restrict__ g,
    const float* __restrict__ b, ushort* __restrict__ oh, ushort* __restrict__ ol) {
  int row = blockIdx.x, tid = threadIdx.x;
  const float* xp = in + (size_t)row * 768;
  float v0 = xp[tid], v1 = xp[tid + 256], v2 = xp[tid + 512];
  float s = v0 + v1 + v2;
  float sq = v0 * v0 + v1 * v1 + v2 * v2;
  __shared__ float red[8];
#pragma unroll
  for (int off = 32; off >= 1; off >>= 1) {
    s += __shfl_down(s, off, 64); sq += __shfl_down(sq, off, 64);
  }
  if ((tid & 63) == 0) { red[tid >> 6] = s; red[4 + (tid >> 6)] = sq; }
  __syncthreads();
  s = red[0] + red[1] + red[2] + red[3];
  sq = red[4] + red[5] + red[6] + red[7];
  float m = s * (1.f / 768.f);
  float var = sq * (1.f / 768.f) - m * m;
  float rs = rsqrtf(var + 1e-5f);
  size_t dbase = (size_t)row * 768;
  ushort h, l;
  float y0 = (v0 - m) * rs * g[tid] + b[tid];
  split_bf16(y0, h, l); oh[dbase + tid] = h; ol[dbase + tid] = l;
  float y1 = (v1 - m) * rs * g[tid + 256] + b[tid + 256];
  split_bf16(y1, h, l); oh[dbase + tid + 256] = h; ol[dbase + tid + 256] = l;
  float y2 = (v2 - m) * rs * g[tid + 512] + b[tid + 512];
  split_bf16(y2, h, l); oh[dbase + tid + 512] = h; ol[dbase + tid + 512] = l;
}

// ---------------- MFMA flash attention -------------------------------------
// 64 q-rows/block, 4 waves (16 q-rows each), KV-tile 64, D=48.
// QK^T: 3-pass split (Q pre-scaled). P: hi-only. PV: Ph*Vh + Ph*Vl.
__global__ __launch_bounds__(256) void attn_mfma(
    const ushort* __restrict__ Qh, const ushort* __restrict__ Ql,
    const ushort* __restrict__ Kh, const ushort* __restrict__ Kl,
    const ushort* __restrict__ Vh, const ushort* __restrict__ Vl,
    ushort* __restrict__ Oh, ushort* __restrict__ Ol) {
  const int S = 834;
  __shared__ ushort sm[29952];
  ushort* Qs = sm;           // 2 planes x 64 x 72
  ushort* Ks = sm + 9216;    // 2 planes x 64 x 72
  ushort* Vt = sm + 18432;   // 2 planes x 48 x 72 (transposed: [d][kv])
  ushort* Ps = sm + 25344;   // 1 plane  x 64 x 72
  const int tid = threadIdx.x;
  const int wave = tid >> 6, lane = tid & 63;
  const int lrow = lane & 15, kq = lane >> 4;
  const int qt = blockIdx.x, head = blockIdx.y, n = blockIdx.z;
  const size_t base = ((size_t)n * S) * 768 + head * 48;

  for (int e = tid; e < 18432; e += 256) sm[e] = 0;
  __syncthreads();
  if (tid < 128) {
    int r = tid >> 1, p = tid & 1;
    int q = qt * 64 + r;
    if (q < S) {
      const ushort* s = (p ? Ql : Qh) + base + (size_t)q * 768;
      ushort* d = &Qs[p * 4608 + r * 72];
#pragma unroll
      for (int seg = 0; seg < 6; seg++)
        *(uint4*)(void*)(d + seg * 8) = *(const uint4*)(const void*)(s + seg * 8);
    }
  }
  __syncthreads();

  bf16x8 aq[2][2];
#pragma unroll
  for (int p = 0; p < 2; p++)
#pragma unroll
    for (int c = 0; c < 2; c++)
      aq[p][c] = *(const bf16x8*)&Qs[p * 4608 + (wave * 16 + lrow) * 72 + c * 32 + kq * 8];

  float m4[4], l4[4];
  f32x4 accO[3];
#pragma unroll
  for (int r = 0; r < 4; r++) { m4[r] = -1e30f; l4[r] = 0.f; }
#pragma unroll
  for (int d = 0; d < 3; d++) accO[d] = (f32x4)0.f;

  for (int kt = 0; kt < S; kt += 64) {
    __syncthreads();
    if (tid < 128) {
      int r = tid >> 1, p = tid & 1;
      int ki = kt + r;
      if (ki < S) {
        const ushort* s = (p ? Kl : Kh) + base + (size_t)ki * 768;
        ushort* d = &Ks[p * 4608 + r * 72];
#pragma unroll
        for (int seg = 0; seg < 6; seg++)
          *(uint4*)(void*)(d + seg * 8) = *(const uint4*)(const void*)(s + seg * 8);
      }
    }
    for (int e = tid; e < 768; e += 256) {
      int p = e >= 384;
      int rem = e - p * 384;
      int kv = rem / 6, seg = rem - kv * 6;
      if (kt + kv < S) {
        uint4 d = *(const uint4*)(const void*)((p ? Vl : Vh) + base +
                                               (size_t)(kt + kv) * 768 + seg * 8);
        ushort* dst = &Vt[p * 3456 + kv];
        uint w[4] = {d.x, d.y, d.z, d.w};
#pragma unroll
        for (int u = 0; u < 4; u++) {
          dst[(seg * 8 + u * 2 + 0) * 72] = (ushort)(w[u] & 0xFFFFu);
          dst[(seg * 8 + u * 2 + 1) * 72] = (ushort)(w[u] >> 16);
        }
      }
    }
    __syncthreads();

    // QK^T
    f32x4 s4[4];
#pragma unroll
    for (int ni = 0; ni < 4; ni++) s4[ni] = (f32x4)0.f;
#pragma unroll
    for (int ni = 0; ni < 4; ni++) {
      bf16x8 bk[2][2];
#pragma unroll
      for (int p = 0; p < 2; p++)
#pragma unroll
        for (int c = 0; c < 2; c++)
          bk[p][c] = *(const bf16x8*)&Ks[p * 4608 + (ni * 16 + lrow) * 72 + c * 32 + kq * 8];
#pragma unroll
      for (int c = 0; c < 2; c++)
        s4[ni] = __builtin_amdgcn_mfma_f32_16x16x32_bf16(aq[0][c], bk[0][c], s4[ni], 0, 0, 0);
#pragma unroll
      for (int c = 0; c < 2; c++)
        s4[ni] = __builtin_amdgcn_mfma_f32_16x16x32_bf16(aq[0][c], bk[1][c], s4[ni], 0, 0, 0);
#pragma unroll
      for (int c = 0; c < 2; c++)
        s4[ni] = __builtin_amdgcn_mfma_f32_16x16x32_bf16(aq[1][c], bk[0][c], s4[ni], 0, 0, 0);
    }

    // online softmax (lane rows: kq*4 + r)
    bool valid[4];
#pragma unroll
    for (int ni = 0; ni < 4; ni++) valid[ni] = (kt + ni * 16 + lrow) < S;
    float pv[4][4];
#pragma unroll
    for (int r = 0; r < 4; r++) {
      float sv[4], mx = -1e30f;
#pragma unroll
      for (int ni = 0; ni < 4; ni++) {
        sv[ni] = valid[ni] ? s4[ni][r] : -1e30f;
        mx = fmaxf(mx, sv[ni]);
      }
#pragma unroll
      for (int off = 8; off >= 1; off >>= 1) mx = fmaxf(mx, __shfl_xor(mx, off, 64));
      float mnew = fmaxf(m4[r], mx);
      float al = __expf(m4[r] - mnew);
      float ps = 0.f;
#pragma unroll
      for (int ni = 0; ni < 4; ni++) {
        float p = valid[ni] ? __expf(sv[ni] - mnew) : 0.f;
        pv[ni][r] = p; ps += p;
      }
#pragma unroll
      for (int off = 8; off >= 1; off >>= 1) ps += __shfl_xor(ps, off, 64);
      l4[r] = l4[r] * al + ps;
      m4[r] = mnew;
#pragma unroll
      for (int d = 0; d < 3; d++) accO[d][r] *= al;
    }
    // write P (hi only), wave-local region
#pragma unroll
    for (int ni = 0; ni < 4; ni++)
#pragma unroll
      for (int r = 0; r < 4; r++)
        Ps[(wave * 16 + kq * 4 + r) * 72 + ni * 16 + lrow] = bf16_rnd(pv[ni][r]);

    // PV
    bf16x8 ap[2];
#pragma unroll
    for (int c = 0; c < 2; c++)
      ap[c] = *(const bf16x8*)&Ps[(wave * 16 + lrow) * 72 + c * 32 + kq * 8];
#pragma unroll
    for (int d = 0; d < 3; d++) {
      bf16x8 bv[2][2];
#pragma unroll
      for (int p = 0; p < 2; p++)
#pragma unroll
        for (int c = 0; c < 2; c++)
          bv[p][c] = *(const bf16x8*)&Vt[p * 3456 + (d * 16 + lrow) * 72 + c * 32 + kq * 8];
#pragma unroll
      for (int c = 0; c < 2; c++)
        accO[d] = __builtin_amdgcn_mfma_f32_16x16x32_bf16(ap[c], bv[0][c], accO[d], 0, 0, 0);
#pragma unroll
      for (int c = 0; c < 2; c++)
        accO[d] = __builtin_amdgcn_mfma_f32_16x16x32_bf16(ap[c], bv[1][c], accO[d], 0, 0, 0);
    }
  }

#pragma unroll
  for (int r = 0; r < 4; r++) {
    int q = qt * 64 + wave * 16 + kq * 4 + r;
    if (q >= S) continue;
    float inv = 1.f / l4[r];
#pragma unroll
    for (int d = 0; d < 3; d++) {
      float v = accO[d][r] * inv;
      ushort h, l;
      split_bf16(v, h, l);
      size_t oi = base + (size_t)q * 768 + d * 16 + lrow;
      Oh[oi] = h; Ol[oi] = l;
    }
  }
}

// ---------------- GRU (torch cell) + masked-mean head ----------------------
__global__ __launch_bounds__(64) void gru_kernel(
    const float* __restrict__ gx, const float* __restrict__ whh,
    const float* __restrict__ bhh, const float* __restrict__ qh_w,
    const float* __restrict__ qh_b, const int* __restrict__ fea_len,
    float* __restrict__ out) {
  int n = blockIdx.x;
  int lane = threadIdx.x;
  bool lo = lane < 32;
  float w1[32], w2[32];
#pragma unroll
  for (int i = 0; i < 32; i++) w1[i] = whh[lane * 32 + i];
#pragma unroll
  for (int i = 0; i < 32; i++) w2[i] = lo ? whh[(64 + lane) * 32 + i] : 0.f;
  float bh1 = bhh[lane];
  float bh2 = lo ? bhh[64 + lane] : 0.f;
  float qw  = lo ? qh_w[lane] : 0.f;
  float h_all[32];
#pragma unroll
  for (int i = 0; i < 32; i++) h_all[i] = 0.f;
  float hown = 0.f, acc = 0.f;
  int L = fea_len[n] + 834;
  const float* gb = gx + (size_t)n * 1034 * 96;
  for (int t = 0; t < 1034; t++) {
    if (t >= L) break;
    const float* g = gb + (size_t)t * 96;
    float g1 = g[lane];
    float g2 = lo ? g[64 + lane] : 0.f;
    float gh1 = bh1, gh2 = bh2;
#pragma unroll
    for (int i = 0; i < 32; i++) {
      gh1 = fmaf(h_all[i], w1[i], gh1);
      gh2 = fmaf(h_all[i], w2[i], gh2);
    }
    float s1 = g1 + gh1;
    float szg = __shfl(s1, (lane + 32) & 63, 64);
    float rg = 1.f / (1.f + expf(-s1));
    float zg = 1.f / (1.f + expf(-szg));
    float nn = tanhf(fmaf(rg, gh2, g2));
    float hn = (1.f - zg) * nn + zg * hown;
    if (lo) { hown = hn; acc = fmaf(hn, qw, acc); }
#pragma unroll
    for (int i = 0; i < 32; i++) h_all[i] = __shfl(hn, i, 64);
  }
#pragma unroll
  for (int off = 16; off >= 1; off >>= 1) acc += __shfl_down(acc, off, 64);
  if (lane == 0) out[n] = acc / (float)L + qh_b[0];
}

// ---------------------------------------------------------------------------
extern "C" void kernel_launch(void* const* d_in, const int* in_sizes, int n_in,
                              void* d_out, int out_size, void* d_ws, size_t ws_size,
                              hipStream_t stream) {
  const float* x        = (const float*)d_in[0];
  const float* spa_feas = (const float*)d_in[1];
  const int*   fea_len  = (const int*)d_in[2];
  const float* pos_emb  = (const float*)d_in[3];
  const float* cls_tok  = (const float*)d_in[4];
  const float* conv_w   = (const float*)d_in[5];
  const float* conv_b   = (const float*)d_in[6];
  const float* gn_g     = (const float*)d_in[7];
  const float* gn_b     = (const float*)d_in[8];
  const float* pin_w    = (const float*)d_in[9];
  const float* pin_b    = (const float*)d_in[10];
  const float* ln_g[3]  = {(const float*)d_in[11], (const float*)d_in[13], (const float*)d_in[15]};
  const float* ln_b[3]  = {(const float*)d_in[12], (const float*)d_in[14], (const float*)d_in[16]};
  const float* wq[2] = {(const float*)d_in[17], (const float*)d_in[22]};
  const float* wk[2] = {(const float*)d_in[18], (const float*)d_in[23]};
  const float* wv[2] = {(const float*)d_in[19], (const float*)d_in[24]};
  const float* wo[2] = {(const float*)d_in[20], (const float*)d_in[25]};
  const float* bo[2] = {(const float*)d_in[21], (const float*)d_in[26]};
  const float* ff_w1 = (const float*)d_in[27];
  const float* ff_b1 = (const float*)d_in[28];
  const float* ff_w2 = (const float*)d_in[29];
  const float* ff_b2 = (const float*)d_in[30];
  const float* pout_w = (const float*)d_in[31];
  const float* pout_b = (const float*)d_in[32];
  const float* spa_w  = (const float*)d_in[33];
  const float* spa_b  = (const float*)d_in[34];
  const float* gru_wih = (const float*)d_in[35];
  const float* gru_whh = (const float*)d_in[36];
  const float* gru_bih = (const float*)d_in[37];
  const float* gru_bhh = (const float*)d_in[38];
  const float* qh_w = (const float*)d_in[39];
  const float* qh_b = (const float*)d_in[40];
  float* outp = (float*)d_out;

  // ---- workspace: fp32 seq + z, then ushort arena R (same 203 MiB total) --
  float* ws  = (float*)d_ws;
  float* seq = ws;                 // 6,352,896 fl
  float* z   = seq + 6352896;      // 5,124,096 fl
  ushort* R  = (ushort*)(ws + 11476992);  // 83,573,760 ushorts

  // encoder-phase cursor layout
  size_t co = 0;
  ushort* pinH = R + co; co += 589824; ushort* pinL = R + co; co += 589824;
  ushort *wqH[2], *wqL[2], *wkH[2], *wkL[2], *wvH[2], *wvL[2], *woH[2], *woL[2];
  for (int l = 0; l < 2; l++) {
    wqH[l] = R + co; co += 589824; wqL[l] = R + co; co += 589824;
    wkH[l] = R + co; co += 589824; wkL[l] = R + co; co += 589824;
    wvH[l] = R + co; co += 589824; wvL[l] = R + co; co += 589824;
    woH[l] = R + co; co += 589824; woL[l] = R + co; co += 589824;
  }
  ushort* aPh = R + co; co += 5124096; ushort* aPl = R + co; co += 5124096;
  ushort* QPh = R + co; co += 5124096; ushort* QPl = R + co; co += 5124096;
  ushort* KPh = R + co; co += 5124096; ushort* KPl = R + co; co += 5124096;
  ushort* VPh = R + co; co += 5124096; ushort* VPl = R + co; co += 5124096;
  ushort* oPh = R + co; co += 5124096; ushort* oPl = R + co; co += 5124096;
  // tokenize tail scratch
  ushort* colH = R + co; co += 2709504; ushort* colL = R + co; co += 2709504;
  ushort* cwH  = R + co; co += 1179648; ushort* cwL  = R + co; co += 1179648;
  ushort* w1rH = R + co; co += 589824;  ushort* w1rL = R + co; co += 589824;
  ushort* w2rH = R + co; co += 1327104; ushort* w2rL = R + co; co += 1327104;
  // (co ~= 73.5M <= 83,573,760)

  // FFN-phase fixed offsets (overlap encoder regions, all dead by then).
  // fm8: 8 slots x 842 rows x 3072; zs: 8 x 842 x 768; ffw: one half-weight.
  // Peak = 20,692,992*2 + 5,173,248*2 + 10,616,832*2 = 72,966,144 <= 83,573,760.
  ushort* fmH  = R;                ushort* fmL  = R + 20692992;
  ushort* zsH  = R + 41385984;     ushort* zsL  = R + 46559232;
  ushort* ffwH = R + 51732480;     ushort* ffwL = R + 62349312;
  // post-FFN fixed offsets (overlap FFN regions, dead after conv2)
  ushort* zPh = R + 40992768;     ushort* zPl = R + 46116864;
  ushort* poutH = R + 51240960;   ushort* poutL = R + 51830784;
  ushort* spaWH = R + 52420608;   ushort* spaWL = R + 53993472;
  ushort* wihH = R + 55566336;    ushort* wihL = R + 55640064;
  ushort* spaInH = R + 55713792;  ushort* spaInL = R + 58990592;
  ushort* seqPh = R;              ushort* seqPl = R + 6352896;
  float* gx = (float*)(R + 12705792);

  const float QSCALE = 0.14433756729740644f;  // 48^-0.5

  // ---- tokenize ----
  resize_w_split<<<2304, 256, 0, stream>>>(conv_w, w1rH, w1rL, 16, 4, 4);
  resize_w_split<<<5184, 256, 0, stream>>>(conv_w, w2rH, w2rL, 4, 12, 12);
  wsplit_kernel<<<1152, 256, 0, stream>>>(conv_w, cwH, cwL, 294912);
  im2col_split<<<9408, 256, 0, stream>>>(x, colH, colL, 1568, 1536, 196, 8, 8, 8, 16, 32, 32);
  gemm_bf3<3><<<dim3(6, 13), 256, 0, stream>>>(colH, colL, cwH, cwL, 1568, 768, 1536,
      conv_b, nullptr, 1.f, seq, nullptr, nullptr, 196, 1, 768);
  im2col_split<<<10584, 256, 0, stream>>>(x, colH, colL, 3528, 768, 441, 16, 4, 4, 6, 32, 32);
  gemm_bf3<3><<<dim3(6, 28), 256, 0, stream>>>(colH, colL, w1rH, w1rL, 3528, 768, 768,
      conv_b + 768, nullptr, 1.f, seq, nullptr, nullptr, 441, 197, 768);
  im2col_split<<<10584, 256, 0, stream>>>(x, colH, colL, 1568, 1728, 196, 4, 12, 12, 16, 32, 32);
  gemm_bf3<3><<<dim3(6, 13), 256, 0, stream>>>(colH, colL, w2rH, w2rL, 1568, 768, 1728,
      conv_b + 1536, nullptr, 1.f, seq, nullptr, nullptr, 196, 638, 768);
  addpos_kernel<<<20016, 256, 0, stream>>>(seq, pos_emb, cls_tok);

  // ---- encoder weight splits ----
  wsplit_kernel<<<576, 256, 0, stream>>>(pin_w, pinH, pinL, 147456);
  for (int l = 0; l < 2; l++) {
    wsplit_kernel<<<576, 256, 0, stream>>>(wq[l], wqH[l], wqL[l], 147456);
    wsplit_kernel<<<576, 256, 0, stream>>>(wk[l], wkH[l], wkL[l], 147456);
    wsplit_kernel<<<576, 256, 0, stream>>>(wv[l], wvH[l], wvL[l], 147456);
    wsplit_kernel<<<576, 256, 0, stream>>>(wo[l], woH[l], woL[l], 147456);
  }

  // ---- temporal encoder ----
  groupnorm_split<<<256, 256, 0, stream>>>(seq, gn_g, gn_b, aPh, aPl);
  gemm_bf3<0><<<dim3(6, 53), 256, 0, stream>>>(aPh, aPl, pinH, pinL, 6672, 768, 768,
      pin_b, nullptr, 1.f, z, nullptr, nullptr, 0, 0, 768);

  for (int l = 0; l < 2; l++) {
    ln_rows_split<<<6672, 256, 0, stream>>>(z, ln_g[l], ln_b[l], aPh, aPl);
    gemm_bf3<2><<<dim3(6, 53), 256, 0, stream>>>(aPh, aPl, wqH[l], wqL[l], 6672, 768, 768,
        nullptr, nullptr, QSCALE, nullptr, QPh, QPl, 0, 0, 768);
    gemm_bf3<2><<<dim3(6, 53), 256, 0, stream>>>(aPh, aPl, wkH[l], wkL[l], 6672, 768, 768,
        nullptr, nullptr, 1.f, nullptr, KPh, KPl, 0, 0, 768);
    gemm_bf3<2><<<dim3(6, 53), 256, 0, stream>>>(aPh, aPl, wvH[l], wvL[l], 6672, 768, 768,
        nullptr, nullptr, 1.f, nullptr, VPh, VPl, 0, 0, 768);
    attn_mfma<<<dim3(14, 16, 8), 256, 0, stream>>>(QPh, QPl, KPh, KPl, VPh, VPl, oPh, oPl);
    gemm_bf3<1><<<dim3(6, 53), 256, 0, stream>>>(oPh, oPl, woH[l], woL[l], 6672, 768, 768,
        bo[l], z, 1.f, z, nullptr, nullptr, 0, 0, 768);
  }

  // ---- FFN (conv1d k=9), all 8 samples per dispatch ----
  // conv1: two J-halves (weight slab 1536x768x9 fits ffw region).
  // conv2: two K-halves accumulating into z (z pre-holds the residual).
  ln_split_kernel<<<6672, 256, 0, stream>>>(z, ln_g[2], ln_b[2], zsH, zsL);
  pad_zero8<<<960, 256, 0, stream>>>(zsH, zsL, fmH, fmL);
  for (int jh = 0; jh < 2; jh++) {
    wprep_kernel<<<41472, 256, 0, stream>>>(ff_w1, ffwH, ffwL, 1536, jh * 1536, 768, 0, 768);
    conv_mfma<64, 64, 32, 1><<<dim3(7, 24, 8), 256, 0, stream>>>(
        zsH, zsL, ffwH, ffwL, 768, 0, 768, 1536, ff_b1, jh * 1536, fmH, fmL, nullptr);
  }
  for (int kh = 0; kh < 2; kh++) {
    wprep_kernel<<<41472, 256, 0, stream>>>(ff_w2, ffwH, ffwL, 768, 0, 1536, kh * 1536, 3072);
    conv_mfma<64, 32, 32, 2><<<dim3(14, 12, 8), 256, 0, stream>>>(
        fmH, fmL, ffwH, ffwL, 3072, kh * 1536, 1536, 768,
        (kh == 1) ? ff_b2 : nullptr, 0, nullptr, nullptr, z);
  }

  // ---- post: splits, pout + spa into seq (+planes), GRU ----
  wsplit_kernel<<<5005, 256, 0, stream>>>(z, zPh, zPl, 1281024);
  wsplit_kernel<<<576, 256, 0, stream>>>(pout_w, poutH, poutL, 147456);
  wsplit_kernel<<<1536, 256, 0, stream>>>(spa_w, spaWH, spaWL, 393216);
  wsplit_kernel<<<72, 256, 0, stream>>>(gru_wih, wihH, wihL, 18432);
  wsplit_kernel<<<3200, 256, 0, stream>>>(spa_feas, spaInH, spaInL, 819200);
  gemm_bf3<3><<<dim3(6, 53), 256, 0, stream>>>(zPh, zPl, poutH, poutL, 6672, 768, 768,
      pout_b, seq, 1.f, seq, seqPh, seqPl, 834, 0, 768);
  gemm_bf3<3><<<dim3(6, 13), 256, 0, stream>>>(spaInH, spaInL, spaWH, spaWL, 1600, 768, 2048,
      spa_b, nullptr, 1.f, seq, seqPh, seqPl, 200, 834, 768);
  gemm_bf3<0><<<dim3(1, 65), 256, 0, stream>>>(seqPh, seqPl, wihH, wihL, 8272, 96, 768,
      gru_bih, nullptr, 1.f, gx, nullptr, nullptr, 0, 0, 96);
  gru_kernel<<<8, 64, 0, stream>>>(gx, gru_whh, gru_bhh, qh_w, qh_b, fea_len, outp);
}

// Round 2
// 5668.459 us; speedup vs baseline: 1.1015x; 1.1015x over previous
//
#include <hip/hip_runtime.h>

// ---------------------------------------------------------------------------
// Tube_fps forward. All GEMM-shaped compute on split-bf16 3-pass MFMA
// (x = hi + lo bf16; acc += Ah*Bh + Ah*Bl + Al*Bh; dropped term ~2^-16 rel).
// Attention: MFMA flash, P stored hi-only (err ~0.2% on attn out, diluted).
// fp32 state: seq (8,1034,768), z (8,834,768). Everything else bf16 planes.
// FFN conv kernels: 128x128 blocks (MI=NI=4, halves LDS reads/MFMA vs 2x2),
// XCD swizzle z=b&7 so W-tiles stay resident in one XCD's L2.
// ---------------------------------------------------------------------------

typedef short bf16x8 __attribute__((ext_vector_type(8)));
typedef float f32x4 __attribute__((ext_vector_type(4)));

__device__ __forceinline__ void split_bf16(float f, ushort& h, ushort& l) {
  uint u = __float_as_uint(f);
  uint rh = (u + 0x7FFFu + ((u >> 16) & 1u)) & 0xFFFF0000u;
  h = (ushort)(rh >> 16);
  float fl = f - __uint_as_float(rh);
  uint ul = __float_as_uint(fl);
  l = (ushort)((ul + 0x7FFFu + ((ul >> 16) & 1u)) >> 16);
}

__device__ __forceinline__ ushort bf16_rnd(float f) {
  uint u = __float_as_uint(f);
  return (ushort)((u + 0x7FFFu + ((u >> 16) & 1u)) >> 16);
}

__device__ __forceinline__ float gelu_exact(float v) {
  return 0.5f * v * (1.f + erff(v * 0.70710678118654752f));
}

// ---------------- generic fp32 -> bf16 hi/lo split -------------------------
__global__ void wsplit_kernel(const float* __restrict__ src, ushort* __restrict__ h,
                              ushort* __restrict__ l, int n4) {
  int i = blockIdx.x * 256 + threadIdx.x;
  if (i >= n4) return;
  float4 v = *(const float4*)(src + (size_t)i * 4);
  ushort hh[4], ll[4];
  split_bf16(v.x, hh[0], ll[0]);
  split_bf16(v.y, hh[1], ll[1]);
  split_bf16(v.z, hh[2], ll[2]);
  split_bf16(v.w, hh[3], ll[3]);
  *(ushort4*)(h + (size_t)i * 4) = make_ushort4(hh[0], hh[1], hh[2], hh[3]);
  *(ushort4*)(l + (size_t)i * 4) = make_ushort4(ll[0], ll[1], ll[2], ll[3]);
}

// ---------------- weight trilinear resize (jax.image.resize, antialias) ----
__device__ __forceinline__ void dim_weights(int j, int O, float* w) {
  float inv = 8.0f / (float)O;
  float ks  = inv > 1.0f ? inv : 1.0f;
  float sf  = ((float)j + 0.5f) * inv - 0.5f;
  float tot = 0.f;
#pragma unroll
  for (int i = 0; i < 8; i++) {
    float xx = fabsf(sf - (float)i) / ks;
    float t  = fmaxf(0.f, 1.f - xx);
    w[i] = t; tot += t;
  }
  float r = 1.f / tot;
#pragma unroll
  for (int i = 0; i < 8; i++) w[i] *= r;
}

__global__ void resize_w_split(const float* __restrict__ src, ushort* __restrict__ dh,
                               ushort* __restrict__ dl, int OD, int OH, int OW) {
  int idx = blockIdx.x * 256 + threadIdx.x;
  int tot = 2304 * OD * OH * OW;
  if (idx >= tot) return;
  int ow = idx % OW; int t = idx / OW;
  int oh = t % OH;   t /= OH;
  int od = t % OD;   int oc = t / OD;
  float wd[8], wh[8], ww[8];
  dim_weights(od, OD, wd);
  dim_weights(oh, OH, wh);
  dim_weights(ow, OW, ww);
  const float* s = src + (size_t)oc * 512;
  float acc = 0.f;
  for (int d = 0; d < 8; d++) {
    if (wd[d] == 0.f) continue;
    for (int h = 0; h < 8; h++) {
      if (wh[h] == 0.f) continue;
      float w2 = wd[d] * wh[h];
      for (int w = 0; w < 8; w++) {
        float w3 = w2 * ww[w];
        if (w3 != 0.f) acc += w3 * s[d * 64 + h * 8 + w];
      }
    }
  }
  ushort h2, l2;
  split_bf16(acc, h2, l2);
  dh[idx] = h2; dl[idx] = l2;
}

// ---------------- im2col (split output) ------------------------------------
__global__ void im2col_split(const float* __restrict__ x, ushort* __restrict__ colh,
                             ushort* __restrict__ coll, int P, int K, int L,
                             int KD, int KH, int KW, int SD, int SH, int SW) {
  int idx = blockIdx.x * 256 + threadIdx.x;
  if (idx >= P * K) return;
  int p = idx / K;  int k = idx - p * K;
  int n = p / L;    int lp = p - n * L;
  int ld = lp / 49; int r = lp - ld * 49;
  int lh = r / 7;   int lw = r - lh * 7;
  int kvol = KD * KH * KW;
  int c = k / kvol; int r2 = k - c * kvol;
  int khw = KH * KW;
  int kd = r2 / khw; int r3 = r2 - kd * khw;
  int kh = r3 / KW;  int kw = r3 - kh * KW;
  int zd = ld * SD + kd, zh = lh * SH + kh, zw = lw * SW + kw;
  float v = x[((((size_t)n * 3 + c) * 64 + zd) * 224 + zh) * 224 + zw];
  ushort h, l;
  split_bf16(v, h, l);
  colh[(size_t)p * K + k] = h;
  coll[(size_t)p * K + k] = l;
}

// ---------------- split-bf16 3-pass MFMA GEMM ------------------------------
// C[i][j] = sum_k A[i][k]*B[j][k].  A: M x K planes, B: N x K planes.
// MODE 0: of[i*ldo+j] = acc (+bias)
// MODE 1: of[i*768+j] = acc + bias + res[i*768+j]
// MODE 2: split(acc*scale) -> oh/ol[i*768+j]
// MODE 3: row = (i/mapL)*1034 + mapOff + i%mapL; v = acc + bias (+res[row*768+j]);
//         of[row*768+j] = v; if oh: split v -> oh/ol[row*768+j]
template <int MODE>
__global__ __launch_bounds__(256) void gemm_bf3(
    const ushort* __restrict__ Ah, const ushort* __restrict__ Al,
    const ushort* __restrict__ Bh, const ushort* __restrict__ Bl,
    int M, int N, int K,
    const float* __restrict__ bias, const float* __restrict__ res, float scale,
    float* __restrict__ of, ushort* __restrict__ oh, ushort* __restrict__ ol,
    int mapL, int mapOff, int ldo) {
  __shared__ ushort ldsA[2 * 128 * 40];
  __shared__ ushort ldsB[2 * 128 * 40];
  const int tid = threadIdx.x;
  const int wave = tid >> 6, lane = tid & 63;
  const int lrow = lane & 15, kq = lane >> 4;
  const int i0 = blockIdx.y * 128;
  const int j0 = blockIdx.x * 128;
  const int wm = (wave & 1) * 64, wn = (wave >> 1) * 64;
  const int sr = tid >> 1, sp = tid & 1;

  f32x4 acc[4][4];
#pragma unroll
  for (int mi = 0; mi < 4; mi++)
#pragma unroll
    for (int ni = 0; ni < 4; ni++) acc[mi][ni] = (f32x4)0.f;

  for (int k0 = 0; k0 < K; k0 += 32) {
    __syncthreads();
    {
      uint4 d0 = make_uint4(0, 0, 0, 0), d1 = d0, d2 = d0, d3 = d0;
      if (i0 + sr < M) {
        const ushort* s = (sp ? Al : Ah) + (size_t)(i0 + sr) * K + k0;
        d0 = *(const uint4*)(const void*)s;
        d1 = *(const uint4*)(const void*)(s + 8);
        d2 = *(const uint4*)(const void*)(s + 16);
        d3 = *(const uint4*)(const void*)(s + 24);
      }
      ushort* dst = &ldsA[sp * 5120 + sr * 40];
      *(uint4*)(void*)dst = d0; *(uint4*)(void*)(dst + 8) = d1;
      *(uint4*)(void*)(dst + 16) = d2; *(uint4*)(void*)(dst + 24) = d3;
    }
    {
      uint4 d0 = make_uint4(0, 0, 0, 0), d1 = d0, d2 = d0, d3 = d0;
      if (j0 + sr < N) {
        const ushort* s = (sp ? Bl : Bh) + (size_t)(j0 + sr) * K + k0;
        d0 = *(const uint4*)(const void*)s;
        d1 = *(const uint4*)(const void*)(s + 8);
        d2 = *(const uint4*)(const void*)(s + 16);
        d3 = *(const uint4*)(const void*)(s + 24);
      }
      ushort* dst = &ldsB[sp * 5120 + sr * 40];
      *(uint4*)(void*)dst = d0; *(uint4*)(void*)(dst + 8) = d1;
      *(uint4*)(void*)(dst + 16) = d2; *(uint4*)(void*)(dst + 24) = d3;
    }
    __syncthreads();
    bf16x8 af[2][4], bf[2][4];
#pragma unroll
    for (int p = 0; p < 2; p++)
#pragma unroll
      for (int mi = 0; mi < 4; mi++)
        af[p][mi] = *(const bf16x8*)&ldsA[p * 5120 + (wm + mi * 16 + lrow) * 40 + kq * 8];
#pragma unroll
    for (int p = 0; p < 2; p++)
#pragma unroll
      for (int ni = 0; ni < 4; ni++)
        bf[p][ni] = *(const bf16x8*)&ldsB[p * 5120 + (wn + ni * 16 + lrow) * 40 + kq * 8];
#pragma unroll
    for (int mi = 0; mi < 4; mi++)
#pragma unroll
      for (int ni = 0; ni < 4; ni++)
        acc[mi][ni] = __builtin_amdgcn_mfma_f32_16x16x32_bf16(
            af[0][mi], bf[0][ni], acc[mi][ni], 0, 0, 0);
#pragma unroll
    for (int mi = 0; mi < 4; mi++)
#pragma unroll
      for (int ni = 0; ni < 4; ni++)
        acc[mi][ni] = __builtin_amdgcn_mfma_f32_16x16x32_bf16(
            af[0][mi], bf[1][ni], acc[mi][ni], 0, 0, 0);
#pragma unroll
    for (int mi = 0; mi < 4; mi++)
#pragma unroll
      for (int ni = 0; ni < 4; ni++)
        acc[mi][ni] = __builtin_amdgcn_mfma_f32_16x16x32_bf16(
            af[1][mi], bf[0][ni], acc[mi][ni], 0, 0, 0);
  }

#pragma unroll
  for (int mi = 0; mi < 4; mi++) {
#pragma unroll
    for (int r = 0; r < 4; r++) {
      int i = i0 + wm + mi * 16 + kq * 4 + r;
      if (i >= M) continue;
#pragma unroll
      for (int ni = 0; ni < 4; ni++) {
        int j = j0 + wn + ni * 16 + lrow;
        if (j >= N) continue;
        float v = acc[mi][ni][r];
        if (MODE == 0) {
          if (bias) v += bias[j];
          of[(size_t)i * ldo + j] = v;
        } else if (MODE == 1) {
          size_t oi = (size_t)i * 768 + j;
          of[oi] = v + bias[j] + res[oi];
        } else if (MODE == 2) {
          v *= scale;
          ushort h, l;
          split_bf16(v, h, l);
          size_t oi = (size_t)i * 768 + j;
          oh[oi] = h; ol[oi] = l;
        } else {
          int nn = i / mapL; int ll = i - nn * mapL;
          size_t oi = ((size_t)(nn * 1034 + mapOff + ll)) * 768 + j;
          v += bias[j];
          if (res) v += res[oi];
          of[oi] = v;
          if (oh) {
            ushort h, l;
            split_bf16(v, h, l);
            oh[oi] = h; ol[oi] = l;
          }
        }
      }
    }
  }
}

// ---------------- weight prep: W[oOff+o][cOff+c][dt] fp32 ------------------
// -> wh/wl[(dt*Jloc + o)*Cloc + c] bf16 hi/lo (a J/C sub-slab, transposed)
__global__ void wprep_kernel(const float* __restrict__ W, ushort* __restrict__ wh,
                             ushort* __restrict__ wl, int Jloc, int oOff,
                             int Cloc, int cOff, int Cfull) {
  size_t idx = (size_t)blockIdx.x * 256 + threadIdx.x;
  size_t tot = (size_t)9 * Jloc * Cloc;
  if (idx >= tot) return;
  int c = (int)(idx % Cloc);
  size_t t2 = idx / Cloc;
  int o = (int)(t2 % Jloc);
  int dt = (int)(t2 / Jloc);
  float f = W[((size_t)(oOff + o) * Cfull + (cOff + c)) * 9 + dt];
  ushort h, l;
  split_bf16(f, h, l);
  wh[idx] = h; wl[idx] = l;
}

// ---------------- ln3 + split into padded bf16 planes ----------------------
__global__ __launch_bounds__(256) void ln_split_kernel(
    const float* __restrict__ in, const float* __restrict__ g,
    const float* __restrict__ b, ushort* __restrict__ oh, ushort* __restrict__ ol) {
  int row = blockIdx.x, tid = threadIdx.x;
  int n = row / 834, t = row - n * 834;
  const float* xp = in + (size_t)row * 768;
  float v0 = xp[tid], v1 = xp[tid + 256], v2 = xp[tid + 512];
  float s = v0 + v1 + v2;
  float sq = v0 * v0 + v1 * v1 + v2 * v2;
  __shared__ float red[8];
#pragma unroll
  for (int off = 32; off >= 1; off >>= 1) {
    s += __shfl_down(s, off, 64); sq += __shfl_down(sq, off, 64);
  }
  if ((tid & 63) == 0) { red[tid >> 6] = s; red[4 + (tid >> 6)] = sq; }
  __syncthreads();
  s = red[0] + red[1] + red[2] + red[3];
  sq = red[4] + red[5] + red[6] + red[7];
  float m = s * (1.f / 768.f);
  float var = sq * (1.f / 768.f) - m * m;
  float rs = rsqrtf(var + 1e-5f);
  size_t dbase = ((size_t)(n * 842 + 4 + t)) * 768;
  ushort h, l;
  float y0 = (v0 - m) * rs * g[tid] + b[tid];
  split_bf16(y0, h, l); oh[dbase + tid] = h; ol[dbase + tid] = l;
  float y1 = (v1 - m) * rs * g[tid + 256] + b[tid + 256];
  split_bf16(y1, h, l); oh[dbase + tid + 256] = h; ol[dbase + tid + 256] = l;
  float y2 = (v2 - m) * rs * g[tid + 512] + b[tid + 512];
  split_bf16(y2, h, l); oh[dbase + tid + 512] = h; ol[dbase + tid + 512] = l;
}

// ---------------- zero pad rows of zs (8 samples) and fmid (8 slots) -------
__global__ void pad_zero8(ushort* __restrict__ zh, ushort* __restrict__ zl,
                          ushort* __restrict__ fh, ushort* __restrict__ fl) {
  int idx = blockIdx.x * 256 + threadIdx.x;
  if (idx < 49152) {
    int c = idx % 768; int t2 = idx / 768;
    int rr = t2 & 7; int n = t2 >> 3;
    int row = (rr < 4) ? rr : (834 + rr);
    size_t d = ((size_t)(n * 842 + row)) * 768 + c;
    zh[d] = 0; zl[d] = 0;
  } else {
    int k = idx - 49152;
    if (k >= 196608) return;
    int c = k % 3072; int t2 = k / 3072;
    int rr = t2 & 7; int n = t2 >> 3;
    int row = (rr < 4) ? rr : (834 + rr);
    size_t d = ((size_t)(n * 842 + row)) * 3072 + c;
    fh[d] = 0; fl[d] = 0;
  }
}

// ---------------- conv1d-as-9-shifted-GEMMs, split-bf16 MFMA ---------------
// Block: 128 t-rows x 128 channels, 4 waves 2x2 (per-wave 64x64, MI=NI=4).
// XCD swizzle: 1-D grid, z = b&7 (sample per XCD), then t fastest, j slow.
// A: padded planes, slot stride 842 rows, row stride CinA, K cols at cOff.
// W: [dt][J][K] planes.
// MODE 1: v = gelu(acc+bias) -> split into fm planes (stride 3072, col jOff+o)
// MODE 2: of[(bz*834+t)*768+o] += acc (+bias if given)   [K-split accumulate]
template <int MODE>
__global__ __launch_bounds__(256) void conv_mfma(
    const ushort* __restrict__ Ah, const ushort* __restrict__ Al,
    const ushort* __restrict__ Wh, const ushort* __restrict__ Wl,
    int CinA, int cOff, int K, int J,
    const float* __restrict__ bias, int jOff,
    ushort* __restrict__ oh, ushort* __restrict__ ol,
    float* __restrict__ of, int nT) {
  constexpr int AR = 136;  // 128 + 8 halo rows
  __shared__ ushort ldsA[2 * AR * 40];
  __shared__ ushort ldsB[2 * 128 * 40];
  const int tid = threadIdx.x;
  const int wave = tid >> 6, lane = tid & 63;
  const int lrow = lane & 15, kq = lane >> 4;
  const int b = blockIdx.x;
  const int bz = b & 7;
  const int r0 = b >> 3;
  const int t0 = (r0 % nT) * 128;
  const int j0 = (r0 / nT) * 128;
  const int wm = (wave & 1) * 64;
  const int wn = (wave >> 1) * 64;

  f32x4 acc[4][4];
#pragma unroll
  for (int mi = 0; mi < 4; mi++)
#pragma unroll
    for (int ni = 0; ni < 4; ni++) acc[mi][ni] = (f32x4)0.f;

  for (int c0 = 0; c0 < K; c0 += 32) {
    __syncthreads();
    for (int task = tid; task < 4 * AR; task += 256) {
      int plane = task >= 2 * AR;
      int rem = task - plane * 2 * AR;
      int rr = rem >> 1, h = rem & 1;
      const ushort* src = (plane ? Al : Ah) +
          ((size_t)(bz * 842 + t0 + rr)) * CinA + cOff + c0 + h * 16;
      uint4 d0 = *(const uint4*)(const void*)src;
      uint4 d1 = *(const uint4*)(const void*)(src + 8);
      ushort* dst = &ldsA[plane * (AR * 40) + rr * 40 + h * 16];
      *(uint4*)(void*)dst = d0;
      *(uint4*)(void*)(dst + 8) = d1;
    }
    for (int dt = 0; dt < 9; dt++) {
      if (dt > 0) __syncthreads();
      for (int task = tid; task < 512; task += 256) {
        int plane = task >= 256;
        int rem = task - plane * 256;
        int o = rem >> 1, h = rem & 1;
        const ushort* src = (plane ? Wl : Wh) +
            ((size_t)(dt * J + j0 + o)) * K + c0 + h * 16;
        uint4 d0 = *(const uint4*)(const void*)src;
        uint4 d1 = *(const uint4*)(const void*)(src + 8);
        ushort* dst = &ldsB[plane * 5120 + o * 40 + h * 16];
        *(uint4*)(void*)dst = d0;
        *(uint4*)(void*)(dst + 8) = d1;
      }
      __syncthreads();
      bf16x8 af[2][4], bf[2][4];
#pragma unroll
      for (int p = 0; p < 2; p++)
#pragma unroll
        for (int mi = 0; mi < 4; mi++)
          af[p][mi] = *(const bf16x8*)&ldsA[p * (AR * 40) +
              (dt + wm + mi * 16 + lrow) * 40 + kq * 8];
#pragma unroll
      for (int p = 0; p < 2; p++)
#pragma unroll
        for (int ni = 0; ni < 4; ni++)
          bf[p][ni] = *(const bf16x8*)&ldsB[p * 5120 +
              (wn + ni * 16 + lrow) * 40 + kq * 8];
#pragma unroll
      for (int mi = 0; mi < 4; mi++)
#pragma unroll
        for (int ni = 0; ni < 4; ni++)
          acc[mi][ni] = __builtin_amdgcn_mfma_f32_16x16x32_bf16(
              af[0][mi], bf[0][ni], acc[mi][ni], 0, 0, 0);
#pragma unroll
      for (int mi = 0; mi < 4; mi++)
#pragma unroll
        for (int ni = 0; ni < 4; ni++)
          acc[mi][ni] = __builtin_amdgcn_mfma_f32_16x16x32_bf16(
              af[0][mi], bf[1][ni], acc[mi][ni], 0, 0, 0);
#pragma unroll
      for (int mi = 0; mi < 4; mi++)
#pragma unroll
        for (int ni = 0; ni < 4; ni++)
          acc[mi][ni] = __builtin_amdgcn_mfma_f32_16x16x32_bf16(
              af[1][mi], bf[0][ni], acc[mi][ni], 0, 0, 0);
    }
  }

#pragma unroll
  for (int ni = 0; ni < 4; ni++) {
    int o = jOff + j0 + wn + ni * 16 + lrow;
    float bo = bias ? bias[o] : 0.f;
#pragma unroll
    for (int mi = 0; mi < 4; mi++) {
#pragma unroll
      for (int r = 0; r < 4; r++) {
        int t = t0 + wm + mi * 16 + kq * 4 + r;
        if (t < 834) {
          float v = acc[mi][ni][r] + bo;
          if (MODE == 1) {
            v = gelu_exact(v);
            ushort h, l;
            split_bf16(v, h, l);
            size_t d = ((size_t)(bz * 842 + 4 + t)) * 3072 + o;
            oh[d] = h; ol[d] = l;
          } else {
            size_t d = ((size_t)(bz * 834 + t)) * 768 + o;
            of[d] += v;
          }
        }
      }
    }
  }
}

// ---------------- cls/pos add ----------------------------------------------
__global__ void addpos_kernel(float* __restrict__ seq, const float* __restrict__ pos,
                              const float* __restrict__ cls) {
  int idx = blockIdx.x * 256 + threadIdx.x;
  if (idx >= 8 * 834 * 768) return;
  int c = idx % 768;
  int t = (idx / 768) % 834;
  int n = idx / (768 * 834);
  size_t off = ((size_t)(n * 1034 + t)) * 768 + c;
  float v = (t == 0) ? cls[c] : seq[off];
  seq[off] = v + pos[(size_t)t * 768 + c];
}

// ---------------- GroupNorm -> split planes --------------------------------
__global__ __launch_bounds__(256) void groupnorm_split(
    const float* __restrict__ seq, const float* __restrict__ g,
    const float* __restrict__ b, ushort* __restrict__ oh, ushort* __restrict__ ol) {
  int blk = blockIdx.x;
  int n = blk >> 5, grp = blk & 31;
  int tid = threadIdx.x;
  float s = 0.f, sq = 0.f;
  for (int e = tid; e < 20016; e += 256) {
    int t = e / 24; int cc = e - t * 24;
    float v = seq[((size_t)(n * 1034 + t)) * 768 + grp * 24 + cc];
    s += v; sq += v * v;
  }
  __shared__ float red[8];
#pragma unroll
  for (int off = 32; off >= 1; off >>= 1) {
    s += __shfl_down(s, off, 64); sq += __shfl_down(sq, off, 64);
  }
  if ((tid & 63) == 0) { red[tid >> 6] = s; red[4 + (tid >> 6)] = sq; }
  __syncthreads();
  s = red[0] + red[1] + red[2] + red[3];
  sq = red[4] + red[5] + red[6] + red[7];
  float m = s * (1.f / 20016.f);
  float var = sq * (1.f / 20016.f) - m * m;
  float rs = rsqrtf(var + 1e-6f);
  for (int e = tid; e < 20016; e += 256) {
    int t = e / 24; int cc = e - t * 24;
    int c = grp * 24 + cc;
    float v = seq[((size_t)(n * 1034 + t)) * 768 + c];
    float y = (v - m) * rs * g[c] + b[c];
    ushort h, l;
    split_bf16(y, h, l);
    size_t d = ((size_t)(n * 834 + t)) * 768 + c;
    oh[d] = h; ol[d] = l;
  }
}

// ---------------- LayerNorm per row -> split planes ------------------------
__global__ __launch_bounds__(256) void ln_rows_split(
    const float* __restrict__ in, const float* __restrict__ g,
    const float* __restrict__ b, ushort* __restrict__ oh, ushort* __restrict__ ol) {
  int row = blockIdx.x, tid = threadIdx.x;
  const float* xp = in + (size_t)row * 768;
  float v0 = xp[tid], v1 = xp[tid + 256], v2 = xp[tid + 512];
  float s = v0 + v1 + v2;
  float sq = v0 * v0 + v1 * v1 + v2 * v2;
  __shared__ float red[8];
#pragma unroll
  for (int off = 32; off >= 1; off >>= 1) {
    s += __shfl_down(s, off, 64); sq += __shfl_down(sq, off, 64);
  }
  if ((tid & 63) == 0) { red[tid >> 6] = s; red[4 + (tid >> 6)] = sq; }
  __syncthreads();
  s = red[0] + red[1] + red[2] + red[3];
  sq = red[4] + red[5] + red[6] + red[7];
  float m = s * (1.f / 768.f);
  float var = sq * (1.f / 768.f) - m * m;
  float rs = rsqrtf(var + 1e-5f);
  size_t dbase = (size_t)row * 768;
  ushort h, l;
  float y0 = (v0 - m) * rs * g[tid] + b[tid];
  split_bf16(y0, h, l); oh[dbase + tid] = h; ol[dbase + tid] = l;
  float y1 = (v1 - m) * rs * g[tid + 256] + b[tid + 256];
  split_bf16(y1, h, l); oh[dbase + tid + 256] = h; ol[dbase + tid + 256] = l;
  float y2 = (v2 - m) * rs * g[tid + 512] + b[tid + 512];
  split_bf16(y2, h, l); oh[dbase + tid + 512] = h; ol[dbase + tid + 512] = l;
}

// ---------------- MFMA flash attention -------------------------------------
// 64 q-rows/block, 4 waves (16 q-rows each), KV-tile 64, D=48.
// QK^T: 3-pass split (Q pre-scaled). P: hi-only. PV: Ph*Vh + Ph*Vl.
__global__ __launch_bounds__(256) void attn_mfma(
    const ushort* __restrict__ Qh, const ushort* __restrict__ Ql,
    const ushort* __restrict__ Kh, const ushort* __restrict__ Kl,
    const ushort* __restrict__ Vh, const ushort* __restrict__ Vl,
    ushort* __restrict__ Oh, ushort* __restrict__ Ol) {
  const int S = 834;
  __shared__ ushort sm[29952];
  ushort* Qs = sm;           // 2 planes x 64 x 72
  ushort* Ks = sm + 9216;    // 2 planes x 64 x 72
  ushort* Vt = sm + 18432;   // 2 planes x 48 x 72 (transposed: [d][kv])
  ushort* Ps = sm + 25344;   // 1 plane  x 64 x 72
  const int tid = threadIdx.x;
  const int wave = tid >> 6, lane = tid & 63;
  const int lrow = lane & 15, kq = lane >> 4;
  const int qt = blockIdx.x, head = blockIdx.y, n = blockIdx.z;
  const size_t base = ((size_t)n * S) * 768 + head * 48;

  for (int e = tid; e < 18432; e += 256) sm[e] = 0;
  __syncthreads();
  if (tid < 128) {
    int r = tid >> 1, p = tid & 1;
    int q = qt * 64 + r;
    if (q < S) {
      const ushort* s = (p ? Ql : Qh) + base + (size_t)q * 768;
      ushort* d = &Qs[p * 4608 + r * 72];
#pragma unroll
      for (int seg = 0; seg < 6; seg++)
        *(uint4*)(void*)(d + seg * 8) = *(const uint4*)(const void*)(s + seg * 8);
    }
  }
  __syncthreads();

  bf16x8 aq[2][2];
#pragma unroll
  for (int p = 0; p < 2; p++)
#pragma unroll
    for (int c = 0; c < 2; c++)
      aq[p][c] = *(const bf16x8*)&Qs[p * 4608 + (wave * 16 + lrow) * 72 + c * 32 + kq * 8];

  float m4[4], l4[4];
  f32x4 accO[3];
#pragma unroll
  for (int r = 0; r < 4; r++) { m4[r] = -1e30f; l4[r] = 0.f; }
#pragma unroll
  for (int d = 0; d < 3; d++) accO[d] = (f32x4)0.f;

  for (int kt = 0; kt < S; kt += 64) {
    __syncthreads();
    if (tid < 128) {
      int r = tid >> 1, p = tid & 1;
      int ki = kt + r;
      if (ki < S) {
        const ushort* s = (p ? Kl : Kh) + base + (size_t)ki * 768;
        ushort* d = &Ks[p * 4608 + r * 72];
#pragma unroll
        for (int seg = 0; seg < 6; seg++)
          *(uint4*)(void*)(d + seg * 8) = *(const uint4*)(const void*)(s + seg * 8);
      }
    }
    for (int e = tid; e < 768; e += 256) {
      int p = e >= 384;
      int rem = e - p * 384;
      int kv = rem / 6, seg = rem - kv * 6;
      if (kt + kv < S) {
        uint4 d = *(const uint4*)(const void*)((p ? Vl : Vh) + base +
                                               (size_t)(kt + kv) * 768 + seg * 8);
        ushort* dst = &Vt[p * 3456 + kv];
        uint w[4] = {d.x, d.y, d.z, d.w};
#pragma unroll
        for (int u = 0; u < 4; u++) {
          dst[(seg * 8 + u * 2 + 0) * 72] = (ushort)(w[u] & 0xFFFFu);
          dst[(seg * 8 + u * 2 + 1) * 72] = (ushort)(w[u] >> 16);
        }
      }
    }
    __syncthreads();

    // QK^T
    f32x4 s4[4];
#pragma unroll
    for (int ni = 0; ni < 4; ni++) s4[ni] = (f32x4)0.f;
#pragma unroll
    for (int ni = 0; ni < 4; ni++) {
      bf16x8 bk[2][2];
#pragma unroll
      for (int p = 0; p < 2; p++)
#pragma unroll
        for (int c = 0; c < 2; c++)
          bk[p][c] = *(const bf16x8*)&Ks[p * 4608 + (ni * 16 + lrow) * 72 + c * 32 + kq * 8];
#pragma unroll
      for (int c = 0; c < 2; c++)
        s4[ni] = __builtin_amdgcn_mfma_f32_16x16x32_bf16(aq[0][c], bk[0][c], s4[ni], 0, 0, 0);
#pragma unroll
      for (int c = 0; c < 2; c++)
        s4[ni] = __builtin_amdgcn_mfma_f32_16x16x32_bf16(aq[0][c], bk[1][c], s4[ni], 0, 0, 0);
#pragma unroll
      for (int c = 0; c < 2; c++)
        s4[ni] = __builtin_amdgcn_mfma_f32_16x16x32_bf16(aq[1][c], bk[0][c], s4[ni], 0, 0, 0);
    }

    // online softmax (lane rows: kq*4 + r)
    bool valid[4];
#pragma unroll
    for (int ni = 0; ni < 4; ni++) valid[ni] = (kt + ni * 16 + lrow) < S;
    float pv[4][4];
#pragma unroll
    for (int r = 0; r < 4; r++) {
      float sv[4], mx = -1e30f;
#pragma unroll
      for (int ni = 0; ni < 4; ni++) {
        sv[ni] = valid[ni] ? s4[ni][r] : -1e30f;
        mx = fmaxf(mx, sv[ni]);
      }
#pragma unroll
      for (int off = 8; off >= 1; off >>= 1) mx = fmaxf(mx, __shfl_xor(mx, off, 64));
      float mnew = fmaxf(m4[r], mx);
      float al = __expf(m4[r] - mnew);
      float ps = 0.f;
#pragma unroll
      for (int ni = 0; ni < 4; ni++) {
        float p = valid[ni] ? __expf(sv[ni] - mnew) : 0.f;
        pv[ni][r] = p; ps += p;
      }
#pragma unroll
      for (int off = 8; off >= 1; off >>= 1) ps += __shfl_xor(ps, off, 64);
      l4[r] = l4[r] * al + ps;
      m4[r] = mnew;
#pragma unroll
      for (int d = 0; d < 3; d++) accO[d][r] *= al;
    }
    // write P (hi only), wave-local region
#pragma unroll
    for (int ni = 0; ni < 4; ni++)
#pragma unroll
      for (int r = 0; r < 4; r++)
        Ps[(wave * 16 + kq * 4 + r) * 72 + ni * 16 + lrow] = bf16_rnd(pv[ni][r]);

    // PV
    bf16x8 ap[2];
#pragma unroll
    for (int c = 0; c < 2; c++)
      ap[c] = *(const bf16x8*)&Ps[(wave * 16 + lrow) * 72 + c * 32 + kq * 8];
#pragma unroll
    for (int d = 0; d < 3; d++) {
      bf16x8 bv[2][2];
#pragma unroll
      for (int p = 0; p < 2; p++)
#pragma unroll
        for (int c = 0; c < 2; c++)
          bv[p][c] = *(const bf16x8*)&Vt[p * 3456 + (d * 16 + lrow) * 72 + c * 32 + kq * 8];
#pragma unroll
      for (int c = 0; c < 2; c++)
        accO[d] = __builtin_amdgcn_mfma_f32_16x16x32_bf16(ap[c], bv[0][c], accO[d], 0, 0, 0);
#pragma unroll
      for (int c = 0; c < 2; c++)
        accO[d] = __builtin_amdgcn_mfma_f32_16x16x32_bf16(ap[c], bv[1][c], accO[d], 0, 0, 0);
    }
  }

#pragma unroll
  for (int r = 0; r < 4; r++) {
    int q = qt * 64 + wave * 16 + kq * 4 + r;
    if (q >= S) continue;
    float inv = 1.f / l4[r];
#pragma unroll
    for (int d = 0; d < 3; d++) {
      float v = accO[d][r] * inv;
      ushort h, l;
      split_bf16(v, h, l);
      size_t oi = base + (size_t)q * 768 + d * 16 + lrow;
      Oh[oi] = h; Ol[oi] = l;
    }
  }
}

// ---------------- GRU (torch cell) + masked-mean head ----------------------
__global__ __launch_bounds__(64) void gru_kernel(
    const float* __restrict__ gx, const float* __restrict__ whh,
    const float* __restrict__ bhh, const float* __restrict__ qh_w,
    const float* __restrict__ qh_b, const int* __restrict__ fea_len,
    float* __restrict__ out) {
  int n = blockIdx.x;
  int lane = threadIdx.x;
  bool lo = lane < 32;
  float w1[32], w2[32];
#pragma unroll
  for (int i = 0; i < 32; i++) w1[i] = whh[lane * 32 + i];
#pragma unroll
  for (int i = 0; i < 32; i++) w2[i] = lo ? whh[(64 + lane) * 32 + i] : 0.f;
  float bh1 = bhh[lane];
  float bh2 = lo ? bhh[64 + lane] : 0.f;
  float qw  = lo ? qh_w[lane] : 0.f;
  float h_all[32];
#pragma unroll
  for (int i = 0; i < 32; i++) h_all[i] = 0.f;
  float hown = 0.f, acc = 0.f;
  int L = fea_len[n] + 834;
  const float* gb = gx + (size_t)n * 1034 * 96;
  for (int t = 0; t < 1034; t++) {
    if (t >= L) break;
    const float* g = gb + (size_t)t * 96;
    float g1 = g[lane];
    float g2 = lo ? g[64 + lane] : 0.f;
    float gh1 = bh1, gh2 = bh2;
#pragma unroll
    for (int i = 0; i < 32; i++) {
      gh1 = fmaf(h_all[i], w1[i], gh1);
      gh2 = fmaf(h_all[i], w2[i], gh2);
    }
    float s1 = g1 + gh1;
    float szg = __shfl(s1, (lane + 32) & 63, 64);
    float rg = 1.f / (1.f + expf(-s1));
    float zg = 1.f / (1.f + expf(-szg));
    float nn = tanhf(fmaf(rg, gh2, g2));
    float hn = (1.f - zg) * nn + zg * hown;
    if (lo) { hown = hn; acc = fmaf(hn, qw, acc); }
#pragma unroll
    for (int i = 0; i < 32; i++) h_all[i] = __shfl(hn, i, 64);
  }
#pragma unroll
  for (int off = 16; off >= 1; off >>= 1) acc += __shfl_down(acc, off, 64);
  if (lane == 0) out[n] = acc / (float)L + qh_b[0];
}

// ---------------------------------------------------------------------------
extern "C" void kernel_launch(void* const* d_in, const int* in_sizes, int n_in,
                              void* d_out, int out_size, void* d_ws, size_t ws_size,
                              hipStream_t stream) {
  const float* x        = (const float*)d_in[0];
  const float* spa_feas = (const float*)d_in[1];
  const int*   fea_len  = (const int*)d_in[2];
  const float* pos_emb  = (const float*)d_in[3];
  const float* cls_tok  = (const float*)d_in[4];
  const float* conv_w   = (const float*)d_in[5];
  const float* conv_b   = (const float*)d_in[6];
  const float* gn_g     = (const float*)d_in[7];
  const float* gn_b     = (const float*)d_in[8];
  const float* pin_w    = (const float*)d_in[9];
  const float* pin_b    = (const float*)d_in[10];
  const float* ln_g[3]  = {(const float*)d_in[11], (const float*)d_in[13], (const float*)d_in[15]};
  const float* ln_b[3]  = {(const float*)d_in[12], (const float*)d_in[14], (const float*)d_in[16]};
  const float* wq[2] = {(const float*)d_in[17], (const float*)d_in[22]};
  const float* wk[2] = {(const float*)d_in[18], (const float*)d_in[23]};
  const float* wv[2] = {(const float*)d_in[19], (const float*)d_in[24]};
  const float* wo[2] = {(const float*)d_in[20], (const float*)d_in[25]};
  const float* bo[2] = {(const float*)d_in[21], (const float*)d_in[26]};
  const float* ff_w1 = (const float*)d_in[27];
  const float* ff_b1 = (const float*)d_in[28];
  const float* ff_w2 = (const float*)d_in[29];
  const float* ff_b2 = (const float*)d_in[30];
  const float* pout_w = (const float*)d_in[31];
  const float* pout_b = (const float*)d_in[32];
  const float* spa_w  = (const float*)d_in[33];
  const float* spa_b  = (const float*)d_in[34];
  const float* gru_wih = (const float*)d_in[35];
  const float* gru_whh = (const float*)d_in[36];
  const float* gru_bih = (const float*)d_in[37];
  const float* gru_bhh = (const float*)d_in[38];
  const float* qh_w = (const float*)d_in[39];
  const float* qh_b = (const float*)d_in[40];
  float* outp = (float*)d_out;

  // ---- workspace: fp32 seq + z, then ushort arena R (same 203 MiB total) --
  float* ws  = (float*)d_ws;
  float* seq = ws;                 // 6,352,896 fl
  float* z   = seq + 6352896;      // 5,124,096 fl
  ushort* R  = (ushort*)(ws + 11476992);  // 83,573,760 ushorts

  // encoder-phase cursor layout
  size_t co = 0;
  ushort* pinH = R + co; co += 589824; ushort* pinL = R + co; co += 589824;
  ushort *wqH[2], *wqL[2], *wkH[2], *wkL[2], *wvH[2], *wvL[2], *woH[2], *woL[2];
  for (int l = 0; l < 2; l++) {
    wqH[l] = R + co; co += 589824; wqL[l] = R + co; co += 589824;
    wkH[l] = R + co; co += 589824; wkL[l] = R + co; co += 589824;
    wvH[l] = R + co; co += 589824; wvL[l] = R + co; co += 589824;
    woH[l] = R + co; co += 589824; woL[l] = R + co; co += 589824;
  }
  ushort* aPh = R + co; co += 5124096; ushort* aPl = R + co; co += 5124096;
  ushort* QPh = R + co; co += 5124096; ushort* QPl = R + co; co += 5124096;
  ushort* KPh = R + co; co += 5124096; ushort* KPl = R + co; co += 5124096;
  ushort* VPh = R + co; co += 5124096; ushort* VPl = R + co; co += 5124096;
  ushort* oPh = R + co; co += 5124096; ushort* oPl = R + co; co += 5124096;
  // tokenize tail scratch
  ushort* colH = R + co; co += 2709504; ushort* colL = R + co; co += 2709504;
  ushort* cwH  = R + co; co += 1179648; ushort* cwL  = R + co; co += 1179648;
  ushort* w1rH = R + co; co += 589824;  ushort* w1rL = R + co; co += 589824;
  ushort* w2rH = R + co; co += 1327104; ushort* w2rL = R + co; co += 1327104;
  // (co ~= 73.5M <= 83,573,760)

  // FFN-phase fixed offsets (overlap encoder regions, all dead by then).
  // fm8: 8 slots x 842 rows x 3072; zs: 8 x 842 x 768; ffw: one half-weight.
  // Peak = 20,692,992*2 + 5,173,248*2 + 10,616,832*2 = 72,966,144 <= 83,573,760.
  ushort* fmH  = R;                ushort* fmL  = R + 20692992;
  ushort* zsH  = R + 41385984;     ushort* zsL  = R + 46559232;
  ushort* ffwH = R + 51732480;     ushort* ffwL = R + 62349312;
  // post-FFN fixed offsets (overlap FFN regions, dead after conv2)
  ushort* zPh = R + 40992768;     ushort* zPl = R + 46116864;
  ushort* poutH = R + 51240960;   ushort* poutL = R + 51830784;
  ushort* spaWH = R + 52420608;   ushort* spaWL = R + 53993472;
  ushort* wihH = R + 55566336;    ushort* wihL = R + 55640064;
  ushort* spaInH = R + 55713792;  ushort* spaInL = R + 58990592;
  ushort* seqPh = R;              ushort* seqPl = R + 6352896;
  float* gx = (float*)(R + 12705792);

  const float QSCALE = 0.14433756729740644f;  // 48^-0.5

  // ---- tokenize ----
  resize_w_split<<<2304, 256, 0, stream>>>(conv_w, w1rH, w1rL, 16, 4, 4);
  resize_w_split<<<5184, 256, 0, stream>>>(conv_w, w2rH, w2rL, 4, 12, 12);
  wsplit_kernel<<<1152, 256, 0, stream>>>(conv_w, cwH, cwL, 294912);
  im2col_split<<<9408, 256, 0, stream>>>(x, colH, colL, 1568, 1536, 196, 8, 8, 8, 16, 32, 32);
  gemm_bf3<3><<<dim3(6, 13), 256, 0, stream>>>(colH, colL, cwH, cwL, 1568, 768, 1536,
      conv_b, nullptr, 1.f, seq, nullptr, nullptr, 196, 1, 768);
  im2col_split<<<10584, 256, 0, stream>>>(x, colH, colL, 3528, 768, 441, 16, 4, 4, 6, 32, 32);
  gemm_bf3<3><<<dim3(6, 28), 256, 0, stream>>>(colH, colL, w1rH, w1rL, 3528, 768, 768,
      conv_b + 768, nullptr, 1.f, seq, nullptr, nullptr, 441, 197, 768);
  im2col_split<<<10584, 256, 0, stream>>>(x, colH, colL, 1568, 1728, 196, 4, 12, 12, 16, 32, 32);
  gemm_bf3<3><<<dim3(6, 13), 256, 0, stream>>>(colH, colL, w2rH, w2rL, 1568, 768, 1728,
      conv_b + 1536, nullptr, 1.f, seq, nullptr, nullptr, 196, 638, 768);
  addpos_kernel<<<20016, 256, 0, stream>>>(seq, pos_emb, cls_tok);

  // ---- encoder weight splits ----
  wsplit_kernel<<<576, 256, 0, stream>>>(pin_w, pinH, pinL, 147456);
  for (int l = 0; l < 2; l++) {
    wsplit_kernel<<<576, 256, 0, stream>>>(wq[l], wqH[l], wqL[l], 147456);
    wsplit_kernel<<<576, 256, 0, stream>>>(wk[l], wkH[l], wkL[l], 147456);
    wsplit_kernel<<<576, 256, 0, stream>>>(wv[l], wvH[l], wvL[l], 147456);
    wsplit_kernel<<<576, 256, 0, stream>>>(wo[l], woH[l], woL[l], 147456);
  }

  // ---- temporal encoder ----
  groupnorm_split<<<256, 256, 0, stream>>>(seq, gn_g, gn_b, aPh, aPl);
  gemm_bf3<0><<<dim3(6, 53), 256, 0, stream>>>(aPh, aPl, pinH, pinL, 6672, 768, 768,
      pin_b, nullptr, 1.f, z, nullptr, nullptr, 0, 0, 768);

  for (int l = 0; l < 2; l++) {
    ln_rows_split<<<6672, 256, 0, stream>>>(z, ln_g[l], ln_b[l], aPh, aPl);
    gemm_bf3<2><<<dim3(6, 53), 256, 0, stream>>>(aPh, aPl, wqH[l], wqL[l], 6672, 768, 768,
        nullptr, nullptr, QSCALE, nullptr, QPh, QPl, 0, 0, 768);
    gemm_bf3<2><<<dim3(6, 53), 256, 0, stream>>>(aPh, aPl, wkH[l], wkL[l], 6672, 768, 768,
        nullptr, nullptr, 1.f, nullptr, KPh, KPl, 0, 0, 768);
    gemm_bf3<2><<<dim3(6, 53), 256, 0, stream>>>(aPh, aPl, wvH[l], wvL[l], 6672, 768, 768,
        nullptr, nullptr, 1.f, nullptr, VPh, VPl, 0, 0, 768);
    attn_mfma<<<dim3(14, 16, 8), 256, 0, stream>>>(QPh, QPl, KPh, KPl, VPh, VPl, oPh, oPl);
    gemm_bf3<1><<<dim3(6, 53), 256, 0, stream>>>(oPh, oPl, woH[l], woL[l], 6672, 768, 768,
        bo[l], z, 1.f, z, nullptr, nullptr, 0, 0, 768);
  }

  // ---- FFN (conv1d k=9), all 8 samples per dispatch, 128x128 blocks ----
  // conv1: two J-halves (weight slab 1536x768x9 fits ffw region).
  // conv2: two K-halves accumulating into z (z pre-holds the residual).
  // Grid is 1-D with z=b&7 (XCD swizzle), then t fastest, j slowest.
  ln_split_kernel<<<6672, 256, 0, stream>>>(z, ln_g[2], ln_b[2], zsH, zsL);
  pad_zero8<<<960, 256, 0, stream>>>(zsH, zsL, fmH, fmL);
  for (int jh = 0; jh < 2; jh++) {
    wprep_kernel<<<41472, 256, 0, stream>>>(ff_w1, ffwH, ffwL, 1536, jh * 1536, 768, 0, 768);
    conv_mfma<1><<<8 * 7 * 12, 256, 0, stream>>>(
        zsH, zsL, ffwH, ffwL, 768, 0, 768, 1536, ff_b1, jh * 1536, fmH, fmL, nullptr, 7);
  }
  for (int kh = 0; kh < 2; kh++) {
    wprep_kernel<<<41472, 256, 0, stream>>>(ff_w2, ffwH, ffwL, 768, 0, 1536, kh * 1536, 3072);
    conv_mfma<2><<<8 * 7 * 6, 256, 0, stream>>>(
        fmH, fmL, ffwH, ffwL, 3072, kh * 1536, 1536, 768,
        (kh == 1) ? ff_b2 : nullptr, 0, nullptr, nullptr, z, 7);
  }

  // ---- post: splits, pout + spa into seq (+planes), GRU ----
  wsplit_kernel<<<5005, 256, 0, stream>>>(z, zPh, zPl, 1281024);
  wsplit_kernel<<<576, 256, 0, stream>>>(pout_w, poutH, poutL, 147456);
  wsplit_kernel<<<1536, 256, 0, stream>>>(spa_w, spaWH, spaWL, 393216);
  wsplit_kernel<<<72, 256, 0, stream>>>(gru_wih, wihH, wihL, 18432);
  wsplit_kernel<<<3200, 256, 0, stream>>>(spa_feas, spaInH, spaInL, 819200);
  gemm_bf3<3><<<dim3(6, 53), 256, 0, stream>>>(zPh, zPl, poutH, poutL, 6672, 768, 768,
      pout_b, seq, 1.f, seq, seqPh, seqPl, 834, 0, 768);
  gemm_bf3<3><<<dim3(6, 13), 256, 0, stream>>>(spaInH, spaInL, spaWH, spaWL, 1600, 768, 2048,
      spa_b, nullptr, 1.f, seq, seqPh, seqPl, 200, 834, 768);
  gemm_bf3<0><<<dim3(1, 65), 256, 0, stream>>>(seqPh, seqPl, wihH, wihL, 8272, 96, 768,
      gru_bih, nullptr, 1.f, gx, nullptr, nullptr, 0, 0, 96);
  gru_kernel<<<8, 64, 0, stream>>>(gx, gru_whh, gru_bhh, qh_w, qh_b, fea_len, outp);
}